// Round 1
// baseline (246.799 us; speedup 1.0000x reference)
//
#include <hip/hip_runtime.h>
#include <math.h>

#define EPS 1e-5f

// One block per (b,c) row. 256 threads x 32 contiguous elements = T=8192.
// Per-thread chunk in registers; block-wide exclusive scan of (sum, sumsq)
// via wave64 shuffle scan + cross-wave LDS combine; then sequential replay
// of the chunk computes causal mean/var and normalizes in-register.
__global__ __launch_bounds__(256) void causal_ln_kernel(
    const float* __restrict__ x,
    const float* __restrict__ weight,
    const float* __restrict__ bias,
    float* __restrict__ out,
    int C, int T)
{
    const int row  = blockIdx.x;        // b*C + c
    const int c    = row % C;
    const float wv = weight[c];
    const float bv = bias[c];
    const long long base = (long long)row * (long long)T;

    const int t     = threadIdx.x;      // 0..255
    const int lane  = t & 63;
    const int wid   = t >> 6;           // wave id 0..3
    const int chunk = t * 32;           // first element of this thread's chunk

    // ---- load 32 elements (8 x float4) into registers ----
    const float4* xp = (const float4*)(x + base + chunk);
    float4 v[8];
#pragma unroll
    for (int j = 0; j < 8; ++j) v[j] = xp[j];

    // ---- local chunk sums ----
    float s = 0.f, s2 = 0.f;
#pragma unroll
    for (int j = 0; j < 8; ++j) {
        s  += v[j].x + v[j].y + v[j].z + v[j].w;
        s2 += v[j].x * v[j].x + v[j].y * v[j].y
            + v[j].z * v[j].z + v[j].w * v[j].w;
    }

    // ---- wave64 inclusive scan of (s, s2) ----
    float ws = s, ws2 = s2;
#pragma unroll
    for (int off = 1; off < 64; off <<= 1) {
        float a  = __shfl_up(ws,  off, 64);
        float a2 = __shfl_up(ws2, off, 64);
        if (lane >= off) { ws += a; ws2 += a2; }
    }

    // ---- cross-wave combine (4 waves) ----
    __shared__ float wsum[4], wsum2[4];
    if (lane == 63) { wsum[wid] = ws; wsum2[wid] = ws2; }
    __syncthreads();
    float off1 = 0.f, off2 = 0.f;
#pragma unroll
    for (int k = 0; k < 4; ++k) {
        if (k < wid) { off1 += wsum[k]; off2 += wsum2[k]; }
    }

    // exclusive prefix for this thread = wave-exclusive + prior-wave totals
    float es  = __shfl_up(ws,  1, 64);
    float es2 = __shfl_up(ws2, 1, 64);
    if (lane == 0) { es = 0.f; es2 = 0.f; }
    float run  = off1 + es;
    float run2 = off2 + es2;

    // ---- sequential replay of the chunk: causal mean/var + normalize ----
    float cnt = (float)chunk;
#pragma unroll
    for (int j = 0; j < 8; ++j) {
        float xs[4] = {v[j].x, v[j].y, v[j].z, v[j].w};
#pragma unroll
        for (int i = 0; i < 4; ++i) {
            float xi = xs[i];
            run  += xi;
            run2 += xi * xi;
            cnt  += 1.f;
            float rc   = __builtin_amdgcn_rcpf(cnt);   // 1/count (count exact in fp32)
            float mean = run * rc;
            float var  = run2 * rc - mean * mean;
            var = fmaxf(var, 0.f);                      // guard tiny negative rounding
            float rinv = __builtin_amdgcn_rsqf(var + EPS);
            xs[i] = (xi - mean) * rinv * wv + bv;
        }
        v[j] = make_float4(xs[0], xs[1], xs[2], xs[3]);
    }

    // ---- store 32 elements (8 x float4) ----
    float4* op = (float4*)(out + base + chunk);
#pragma unroll
    for (int j = 0; j < 8; ++j) op[j] = v[j];
}

extern "C" void kernel_launch(void* const* d_in, const int* in_sizes, int n_in,
                              void* d_out, int out_size, void* d_ws, size_t ws_size,
                              hipStream_t stream) {
    const float* x      = (const float*)d_in[0];
    const float* weight = (const float*)d_in[1];
    const float* bias   = (const float*)d_in[2];
    float* out          = (float*)d_out;

    const int C = in_sizes[1];            // 512 (weight is [1,C,1])
    const int T = 8192;                   // time length per row (reference fixed)
    const int rows = in_sizes[0] / T;     // B*C = 4096

    dim3 grid(rows), block(256);
    hipLaunchKernelGGL(causal_ln_kernel, grid, block, 0, stream,
                       x, weight, bias, out, C, T);
}

// Round 2
// 232.790 us; speedup vs baseline: 1.0602x; 1.0602x over previous
//
#include <hip/hip_runtime.h>
#include <math.h>

#define EPS 1e-5f

// One block per (b,c) row, T=8192 floats = 2048 float4s.
// Phase 1: coalesced global->LDS (lane-consecutive float4s), LDS layout
//   padded so each thread's 32-element chunk starts at word t*36 (128B data
//   + 16B pad) -- bank pattern identical to natural stride-1 ds_*_b128.
// Phase 2: each thread reads its contiguous 32-elem chunk from LDS,
//   block-scan of (sum,sumsq), sequential replay normalizes in-register,
//   writes back to same LDS slots.
// Phase 3: coalesced LDS->global store.
__global__ __launch_bounds__(256) void causal_ln_kernel(
    const float* __restrict__ x,
    const float* __restrict__ weight,
    const float* __restrict__ bias,
    float* __restrict__ out,
    int C, int T)
{
    // padded LDS: 256 chunks * 36 words = 9216 words = 36 KB
    __shared__ float lds[256 * 36];
    __shared__ float wsum[4], wsum2[4];

    const int row  = blockIdx.x;        // b*C + c
    const int c    = row % C;
    const float wv = weight[c];
    const float bv = bias[c];
    const long long base = (long long)row * (long long)T;

    const int t    = threadIdx.x;       // 0..255
    const int lane = t & 63;
    const int wid  = t >> 6;            // wave id 0..3

    // ---- Phase 1: coalesced load, scatter into padded LDS ----
    const float4* xg = (const float4*)(x + base);
#pragma unroll
    for (int j = 0; j < 8; ++j) {
        int g = j * 256 + t;                 // global float4 index, coalesced
        float4 f = xg[g];
        int owner  = g >> 3;                 // which thread's chunk
        int within = g & 7;                  // which float4 inside chunk
        *(float4*)&lds[owner * 36 + within * 4] = f;
    }
    __syncthreads();

    // ---- Phase 2a: read own contiguous chunk from LDS ----
    float4 v[8];
#pragma unroll
    for (int j = 0; j < 8; ++j)
        v[j] = *(const float4*)&lds[t * 36 + j * 4];

    // local chunk sums
    float s = 0.f, s2 = 0.f;
#pragma unroll
    for (int j = 0; j < 8; ++j) {
        s  += v[j].x + v[j].y + v[j].z + v[j].w;
        s2 += v[j].x * v[j].x + v[j].y * v[j].y
            + v[j].z * v[j].z + v[j].w * v[j].w;
    }

    // wave64 inclusive scan of (s, s2)
    float ws = s, ws2 = s2;
#pragma unroll
    for (int off = 1; off < 64; off <<= 1) {
        float a  = __shfl_up(ws,  off, 64);
        float a2 = __shfl_up(ws2, off, 64);
        if (lane >= off) { ws += a; ws2 += a2; }
    }

    // cross-wave combine (4 waves)
    if (lane == 63) { wsum[wid] = ws; wsum2[wid] = ws2; }
    __syncthreads();
    float off1 = 0.f, off2 = 0.f;
#pragma unroll
    for (int k = 0; k < 4; ++k) {
        if (k < wid) { off1 += wsum[k]; off2 += wsum2[k]; }
    }

    // exclusive prefix for this thread
    float es  = __shfl_up(ws,  1, 64);
    float es2 = __shfl_up(ws2, 1, 64);
    if (lane == 0) { es = 0.f; es2 = 0.f; }
    float run  = off1 + es;
    float run2 = off2 + es2;

    // ---- Phase 2b: sequential replay, normalize, write back to LDS ----
    float cnt = (float)(t * 32);
#pragma unroll
    for (int j = 0; j < 8; ++j) {
        float xs[4] = {v[j].x, v[j].y, v[j].z, v[j].w};
#pragma unroll
        for (int i = 0; i < 4; ++i) {
            float xi = xs[i];
            run  += xi;
            run2 += xi * xi;
            cnt  += 1.f;
            float rc   = __builtin_amdgcn_rcpf(cnt);
            float mean = run * rc;
            float var  = run2 * rc - mean * mean;
            var = fmaxf(var, 0.f);
            float rinv = __builtin_amdgcn_rsqf(var + EPS);
            xs[i] = (xi - mean) * rinv * wv + bv;
        }
        *(float4*)&lds[t * 36 + j * 4] = make_float4(xs[0], xs[1], xs[2], xs[3]);
    }
    __syncthreads();

    // ---- Phase 3: coalesced gather from padded LDS, store ----
    float4* og = (float4*)(out + base);
#pragma unroll
    for (int j = 0; j < 8; ++j) {
        int g = j * 256 + t;
        int owner  = g >> 3;
        int within = g & 7;
        og[g] = *(const float4*)&lds[owner * 36 + within * 4];
    }
}

extern "C" void kernel_launch(void* const* d_in, const int* in_sizes, int n_in,
                              void* d_out, int out_size, void* d_ws, size_t ws_size,
                              hipStream_t stream) {
    const float* x      = (const float*)d_in[0];
    const float* weight = (const float*)d_in[1];
    const float* bias   = (const float*)d_in[2];
    float* out          = (float*)d_out;

    const int C = in_sizes[1];            // 512 (weight is [1,C,1])
    const int T = 8192;                   // time length per row
    const int rows = in_sizes[0] / T;     // B*C = 4096

    dim3 grid(rows), block(256);
    hipLaunchKernelGGL(causal_ln_kernel, grid, block, 0, stream,
                       x, weight, bias, out, C, T);
}